// Round 5
// baseline (1657.750 us; speedup 1.0000x reference)
//
#include <hip/hip_runtime.h>
#include <hip/hip_bf16.h>
#include <stdint.h>

// ---------------------------------------------------------------------------
// MixModel fused kernel (MI355X / gfx950), round 5.
//
// Round-4 structure (proven correct) with register pressure cut below the
// unified 512 VGPR+AGPR file to kill the 2.6 GB scratch-spill traffic:
// - static features are 0/1 -> per-lane BITMASK bank (6 regs) instead of a
//   72-reg fp16 fragment bank; fragments rebuilt per step with ~30 VALU.
// - snapshot only the 9 message chunks per step (36 regs) instead of all 12
//   B-chunks (48 regs).
// - messages (9x9 chunks, 2 sample tiles) resident in registers (324 regs),
//   C/D fragment == B fragment => free inter-layer transpose (parity scheme).
// - layer bias folded into weight row k=45 (pad lane carries 1.0).
// - weights stream global->LDS via global_load_lds, double-buffered.
// ---------------------------------------------------------------------------

typedef __attribute__((ext_vector_type(4))) float    f32x4;
typedef __attribute__((ext_vector_type(4))) _Float16 f16x4;
typedef __attribute__((ext_vector_type(8))) _Float16 f16x8;
typedef unsigned long long u64;
typedef unsigned int u32;

#define STEP_BYTES 55296           // 9 jt * 6 slices * 64 lanes * 16B
#define CMN_BYTES  45056           // padded; real 41472
#define WS_LAYER   (54*STEP_BYTES) // 2,985,984
#define LDS_TOTAL  (2*STEP_BYTES)  // 110,592

__device__ __forceinline__ unsigned short f2h(float f) {
  return __builtin_bit_cast(unsigned short, (_Float16)f);
}
__device__ __forceinline__ u64 as_u64(f16x4 v) { return __builtin_bit_cast(u64, v); }
__device__ __forceinline__ f16x4 as_f16x4(u64 v) { return __builtin_bit_cast(f16x4, v); }

__device__ __forceinline__ f32x4 mfma16(f16x4 a, f16x4 b, f32x4 c) {
#if __has_builtin(__builtin_amdgcn_mfma_f32_16x16x16f16)
  return __builtin_amdgcn_mfma_f32_16x16x16f16(a, b, c, 0, 0, 0);
#else
  asm("v_mfma_f32_16x16x16_f16 %0, %1, %2, %0" : "+v"(c) : "v"(a), "v"(b));
  return c;
#endif
}

// static feature value for (sample b, position o, padded k-index kidx in [0,48))
// [0..8] mask row o | [9..17] board ch0 row o | [18..26] board ch1 row o
// [27..35] g0 (ch0 row 9) | [36..44] g1 (ch1 row 9) | [45..47] zero pad
__device__ __forceinline__ float static_feat(const float* __restrict__ mask,
                                             const float* __restrict__ board,
                                             int b, int o, int kidx) {
  if (kidx < 9)  return mask [b*81  + o*9 + kidx];
  if (kidx < 18) return board[b*180 +       o*9 + (kidx - 9)];
  if (kidx < 27) return board[b*180 + 90 +  o*9 + (kidx - 18)];
  if (kidx < 36) return board[b*180 +       81 + (kidx - 27)];
  if (kidx < 45) return board[b*180 + 90 +  81 + (kidx - 36)];
  return 0.f;
}

// async stage one step's fragment block into LDS (wave-uniform dest + lane*16)
__device__ __forceinline__ void stage_step(int s, const unsigned char* __restrict__ ws,
                                           unsigned char* dstlds, int tid) {
  const unsigned char* src = (s < 54) ? (ws + (size_t)s * STEP_BYTES)
                                      : (ws + WS_LAYER + (size_t)(s - 54) * CMN_BYTES);
  const int n16 = (s < 54) ? (STEP_BYTES / 16) : (CMN_BYTES / 16);
  const int ubase = tid & ~63;
  for (int k = 0; k * 256 < n16; ++k) {
    const int idx = k * 256 + tid;
    if (idx < n16) {  // wave-uniform branch (n16 % 64 == 0)
      __builtin_amdgcn_global_load_lds(
          (const __attribute__((address_space(1))) void*)(src + (size_t)idx * 16),
          (__attribute__((address_space(3))) void*)(dstlds + (size_t)(k * 256 + ubase) * 16),
          16, 0, 0);
    }
  }
}

// one (layer, position) step: 9 jt output tiles, K=192 as 12 K16 chunks.
// chunk order: 0=st0(bits), 1=st1(bits), 2=stc(+bias lane), 3..11 = messages.
template<int P, int O>
__device__ __forceinline__ void do_position(const unsigned char* __restrict__ wb,
    u64 (&msg)[9][9][2], const u64 (&sb)[2], const u32 (&sb8)[2],
    const f16x4 (&stc)[2], int lane)
{
  // rebuild position-O static fragments from the bitmask bank (values 0/1)
  f16x4 st0[2], st1[2];
#pragma unroll
  for (int t = 0; t < 2; ++t) {
    const u32 byt = (O < 8) ? ((u32)(sb[t] >> (O * 8)) & 0xFFu) : sb8[t];
#pragma unroll
    for (int e = 0; e < 4; ++e) {
      st0[t][e] = (_Float16)(float)((byt >> e) & 1u);
      st1[t][e] = (_Float16)(float)((byt >> (4 + e)) & 1u);
    }
  }

  // snapshot the message chunks (read set == write set within this step)
  u64 msgc[2][9];
#pragma unroll
  for (int t = 0; t < 2; ++t)
#pragma unroll
    for (int i = 0; i < 9; ++i)
      msgc[t][i] = P ? msg[O][i][t] : msg[i][O][t];

  const unsigned char* abase = wb + (size_t)lane * 16;
#pragma unroll
  for (int j = 0; j < 9; ++j) {
    f32x4 acc0 = 0.f, acc1 = 0.f;
#pragma unroll
    for (int sp = 0; sp < 6; ++sp) {
      const f16x8 af = *(const f16x8*)(abase + j * 6144 + sp * 1024);
      const f16x4 alo = __builtin_shufflevector(af, af, 0, 1, 2, 3);
      const f16x4 ahi = __builtin_shufflevector(af, af, 4, 5, 6, 7);
      const int c0 = 2 * sp, c1 = 2 * sp + 1;
      const f16x4 b00 = (c0 == 0) ? st0[0] : (c0 == 2) ? stc[0] : as_f16x4(msgc[0][c0 - 3]);
      const f16x4 b01 = (c0 == 0) ? st0[1] : (c0 == 2) ? stc[1] : as_f16x4(msgc[1][c0 - 3]);
      const f16x4 b10 = (c1 == 1) ? st1[0] : as_f16x4(msgc[0][c1 - 3]);
      const f16x4 b11 = (c1 == 1) ? st1[1] : as_f16x4(msgc[1][c1 - 3]);
      acc0 = mfma16(alo, b00, acc0);
      acc1 = mfma16(alo, b01, acc1);
      acc0 = mfma16(ahi, b10, acc0);
      acc1 = mfma16(ahi, b11, acc1);
    }
    f16x4 h0, h1;
#pragma unroll
    for (int r = 0; r < 4; ++r) {
      h0[r] = (_Float16)fmaxf(acc0[r], 0.f);
      h1[r] = (_Float16)fmaxf(acc1[r], 0.f);
    }
    if (P) { msg[O][j][0] = as_u64(h0); msg[O][j][1] = as_u64(h1); }
    else   { msg[j][O][0] = as_u64(h0); msg[j][O][1] = as_u64(h1); }
  }
}

__global__ __launch_bounds__(256, 1) void mix_main(
    const float* __restrict__ mask, const float* __restrict__ board,
    const float* __restrict__ common_b, const float* __restrict__ wdl_w,
    const float* __restrict__ wdl_b, const unsigned char* __restrict__ ws,
    float* __restrict__ out, int Bt)
{
  extern __shared__ unsigned char lds[];
  const int tid = threadIdx.x;
  const int lane = tid & 63;
  const int wid = tid >> 6;
  const int s15 = lane & 15, hq = lane >> 4;
  const int b0 = blockIdx.x * 128 + wid * 32;

  stage_step(0, ws, lds, tid);   // prologue stage of step 0 (buffer parity 0)

  u64 msg[9][9][2];
#pragma unroll
  for (int a = 0; a < 9; ++a)
#pragma unroll
    for (int b = 0; b < 9; ++b) { msg[a][b][0] = 0ull; msg[a][b][1] = 0ull; }

  // static bitmask bank: bit (o*8 + c*4 + e) of sb[t] (o<8) / sb8[t] (o=8)
  // holds static_feat(b, o, c*16 + 4*hq + e) — all mask/board values are 0/1.
  u64 sb[2] = {0ull, 0ull};
  u32 sb8[2] = {0u, 0u};
#pragma unroll
  for (int t = 0; t < 2; ++t) {
    const int b = b0 + t * 16 + s15;
#pragma unroll
    for (int o = 0; o < 9; ++o)
#pragma unroll
      for (int e = 0; e < 4; ++e) {
        const u32 bit0 = static_feat(mask, board, b, o,      4 * hq + e) > 0.5f;
        const u32 bit1 = static_feat(mask, board, b, o, 16 + 4 * hq + e) > 0.5f;
        if (o < 8) sb[t] |= ((u64)bit0 << (o * 8 + e)) | ((u64)bit1 << (o * 8 + 4 + e));
        else       sb8[t] |= (bit0 << e) | (bit1 << (4 + e));
      }
  }

  // position-independent chunk 2 (g0 tail + g1); pad lane k=45 carries 1.0
  // so the layer bias (stored in weight row 45) rides the MFMA.
  f16x4 stc[2];
#pragma unroll
  for (int t = 0; t < 2; ++t) {
    const int b = b0 + t * 16 + s15;
#pragma unroll
    for (int e = 0; e < 4; ++e) {
      const int kidx = 32 + 4 * hq + e;
      stc[t][e] = (_Float16)((kidx == 45) ? 1.f : static_feat(mask, board, b, 0, kidx));
    }
  }

#define DO_POS(P, O) { \
    asm volatile("s_waitcnt vmcnt(0)" ::: "memory"); \
    __syncthreads(); \
    const int step = base + (P) * 9 + (O); \
    if (step + 1 < 64) \
      stage_step(step + 1, ws, lds + (size_t)((step + 1) & 1) * STEP_BYTES, tid); \
    do_position<P, O>(lds + (size_t)(step & 1) * STEP_BYTES, msg, sb, sb8, stc, lane); \
  }

  for (int dp = 0; dp < 3; ++dp) {
    const int base = dp * 18;
    DO_POS(0,0) DO_POS(0,1) DO_POS(0,2) DO_POS(0,3) DO_POS(0,4)
    DO_POS(0,5) DO_POS(0,6) DO_POS(0,7) DO_POS(0,8)
    DO_POS(1,0) DO_POS(1,1) DO_POS(1,2) DO_POS(1,3) DO_POS(1,4)
    DO_POS(1,5) DO_POS(1,6) DO_POS(1,7) DO_POS(1,8)
  }
#undef DO_POS

  // ---- common layer: (B x 1296) @ (1296 x 145), 10 M-tiles streamed ----
  float pw0[3] = {0.f, 0.f, 0.f}, pw1[3] = {0.f, 0.f, 0.f};
  for (int mt = 0; mt < 10; ++mt) {
    asm volatile("s_waitcnt vmcnt(0)" ::: "memory");
    __syncthreads();
    const int step = 54 + mt;
    if (step + 1 < 64)
      stage_step(step + 1, ws, lds + (size_t)((step + 1) & 1) * STEP_BYTES, tid);
    const unsigned char* cb = lds + (size_t)(step & 1) * STEP_BYTES;
    f32x4 a0 = 0.f, a1 = 0.f;
#pragma unroll
    for (int i = 0; i < 9; ++i) {
#pragma unroll
      for (int p = 0; p < 4; ++p) {
        const f16x8 af = *(const f16x8*)(cb + ((size_t)(i * 4 + p) * 64 + lane) * 16);
        const f16x4 alo = __builtin_shufflevector(af, af, 0, 1, 2, 3);
        const f16x4 ahi = __builtin_shufflevector(af, af, 4, 5, 6, 7);
        a0 = mfma16(alo, as_f16x4(msg[i][2 * p][0]),     a0);
        a1 = mfma16(alo, as_f16x4(msg[i][2 * p][1]),     a1);
        a0 = mfma16(ahi, as_f16x4(msg[i][2 * p + 1][0]), a0);
        a1 = mfma16(ahi, as_f16x4(msg[i][2 * p + 1][1]), a1);
      }
      const f16x4 al = *(const f16x4*)(cb + 36864 + ((size_t)i * 64 + lane) * 8);
      a0 = mfma16(al, as_f16x4(msg[i][8][0]), a0);
      a1 = mfma16(al, as_f16x4(msg[i][8][1]), a1);
    }
#pragma unroll
    for (int r = 0; r < 4; ++r) {
      const int c = mt * 16 + 4 * hq + r;
      const float bias = (c < 145) ? common_b[c] : 0.f;
      const float v0 = a0[r] + bias, v1 = a1[r] + bias;
      if (c < 81) {  // policy (no relu)
        out[(size_t)3 * Bt + (size_t)(b0 + s15) * 81 + c]      = v0;
        out[(size_t)3 * Bt + (size_t)(b0 + 16 + s15) * 81 + c] = v1;
      } else if (c < 145) {  // wdl hidden: relu then tiny matmul accumulation
        const float h0 = fmaxf(v0, 0.f), h1 = fmaxf(v1, 0.f);
        const int cc = c - 81;
#pragma unroll
        for (int w = 0; w < 3; ++w) {
          const float wv = wdl_w[cc * 3 + w];
          pw0[w] += h0 * wv;
          pw1[w] += h1 * wv;
        }
      }
    }
  }

  // reduce wdl partials across the 4 lane-quarters (same sample col)
#pragma unroll
  for (int w = 0; w < 3; ++w) {
    float v0 = pw0[w], v1 = pw1[w];
    v0 += __shfl_xor(v0, 16, 64); v0 += __shfl_xor(v0, 32, 64);
    v1 += __shfl_xor(v1, 16, 64); v1 += __shfl_xor(v1, 32, 64);
    if (hq == 0) {
      const float bb = wdl_b[w];
      out[(size_t)(b0 + s15) * 3 + w]      = v0 + bb;
      out[(size_t)(b0 + 16 + s15) * 3 + w] = v1 + bb;
    }
  }
}

// ---- prologue: layer weights -> fp16 A-fragment order -----------------------
// [d*9+o][jt 9][slice 6][lane 64] x 16B ; e<4 -> kc=2s, e>=4 -> kc=2s+1,
// within-chunk k = 4*hq + (e&3). kidx: 0..44 static, 45 = BIAS row, 46..47
// zero, >=48 -> message k = kidx-3.
__global__ __launch_bounds__(256) void conv_layer_w(const float* __restrict__ lw,
                                                    const float* __restrict__ lb,
                                                    unsigned char* __restrict__ dst) {
  const int gid = blockIdx.x * 256 + threadIdx.x;
  if (gid >= 54 * 9 * 6 * 64) return;
  const int lane = gid & 63;
  const int t = gid >> 6;
  const int kp = t % 6, t2 = t / 6;
  const int jp = t2 % 9, dop = t2 / 9;
  const int m = lane & 15, hq = lane >> 4;
  unsigned short v[8];
#pragma unroll
  for (int e = 0; e < 8; ++e) {
    const int kc = kp * 2 + (e >> 2);
    const int kidx = kc * 16 + 4 * hq + (e & 3);
    float f = 0.f;
    if (kidx < 45)        f = lw[((size_t)dop * 189 + kidx) * 144 + jp * 16 + m];
    else if (kidx == 45)  f = lb[(size_t)dop * 144 + jp * 16 + m];
    else if (kidx >= 48)  f = lw[((size_t)dop * 189 + (kidx - 3)) * 144 + jp * 16 + m];
    v[e] = f2h(f);
  }
  const u32 w0 = (u32)v[0] | ((u32)v[1] << 16);
  const u32 w1 = (u32)v[2] | ((u32)v[3] << 16);
  const u32 w2 = (u32)v[4] | ((u32)v[5] << 16);
  const u32 w3 = (u32)v[6] | ((u32)v[7] << 16);
  *(uint4*)(dst + (size_t)gid * 16) = make_uint4(w0, w1, w2, w3);
}

// ---- prologue: common weights -> fp16 A-fragment order ----------------------
// per mt: [(i*4+p)*64+lane]x16B (pairs ci=i*9+2p, i*9+2p+1), then at 36864:
// [i*64+lane]x8B (leftover ci=i*9+8). c_out padded 145->160 with zeros.
__global__ __launch_bounds__(256) void conv_common_w(const float* __restrict__ cw,
                                                     unsigned char* __restrict__ dst) {
  const int gid = blockIdx.x * 256 + threadIdx.x;
  const int NPAIR = 10 * 36 * 64;
  if (gid < NPAIR) {
    const int lane = gid & 63;
    const int t = gid >> 6;
    const int p = t % 4, t2 = t / 4;
    const int i = t2 % 9, mt = t2 / 9;
    const int m = lane & 15, hq = lane >> 4;
    const int c = mt * 16 + m;
    unsigned short v[8];
#pragma unroll
    for (int e = 0; e < 8; ++e) {
      const int ci = i * 9 + 2 * p + (e >> 2);
      const int k = ci * 16 + 4 * hq + (e & 3);
      v[e] = f2h((c < 145) ? cw[(size_t)k * 145 + c] : 0.f);
    }
    const u32 w0 = (u32)v[0] | ((u32)v[1] << 16);
    const u32 w1 = (u32)v[2] | ((u32)v[3] << 16);
    const u32 w2 = (u32)v[4] | ((u32)v[5] << 16);
    const u32 w3 = (u32)v[6] | ((u32)v[7] << 16);
    *(uint4*)(dst + (size_t)WS_LAYER + (size_t)mt * CMN_BYTES
              + ((size_t)(i * 4 + p) * 64 + lane) * 16) = make_uint4(w0, w1, w2, w3);
  } else if (gid < NPAIR + 10 * 9 * 64) {
    const int g = gid - NPAIR;
    const int lane = g & 63;
    const int t = g >> 6;
    const int i = t % 9, mt = t / 9;
    const int m = lane & 15, hq = lane >> 4;
    const int c = mt * 16 + m;
    unsigned short v[4];
#pragma unroll
    for (int e = 0; e < 4; ++e) {
      const int k = (i * 9 + 8) * 16 + 4 * hq + e;
      v[e] = f2h((c < 145) ? cw[(size_t)k * 145 + c] : 0.f);
    }
    const u32 w0 = (u32)v[0] | ((u32)v[1] << 16);
    const u32 w1 = (u32)v[2] | ((u32)v[3] << 16);
    *(uint2*)(dst + (size_t)WS_LAYER + (size_t)mt * CMN_BYTES + 36864
              + ((size_t)i * 64 + lane) * 8) = make_uint2(w0, w1);
  }
}

extern "C" void kernel_launch(void* const* d_in, const int* in_sizes, int n_in,
                              void* d_out, int out_size, void* d_ws, size_t ws_size,
                              hipStream_t stream) {
  const float* mask     = (const float*)d_in[0];
  const float* board    = (const float*)d_in[1];
  const float* layer_w  = (const float*)d_in[2];
  const float* layer_b  = (const float*)d_in[3];
  const float* common_w = (const float*)d_in[4];
  const float* common_b = (const float*)d_in[5];
  const float* wdl_w    = (const float*)d_in[6];
  const float* wdl_b    = (const float*)d_in[7];
  float* out = (float*)d_out;
  unsigned char* ws = (unsigned char*)d_ws;
  const int Bt = in_sizes[0] / 81;   // 65536

  hipLaunchKernelGGL(conv_layer_w, dim3((54 * 9 * 6 * 64) / 256), dim3(256), 0, stream,
                     layer_w, layer_b, ws);
  hipLaunchKernelGGL(conv_common_w, dim3((10 * (36 + 9) * 64 + 255) / 256), dim3(256),
                     0, stream, common_w, ws);
  (void)hipFuncSetAttribute((const void*)mix_main,
                            hipFuncAttributeMaxDynamicSharedMemorySize, LDS_TOTAL);
  hipLaunchKernelGGL(mix_main, dim3(Bt / 128), dim3(256), LDS_TOTAL, stream,
                     mask, board, common_b, wdl_w, wdl_b, ws, out, Bt);
}

// Round 7
// 847.065 us; speedup vs baseline: 1.9571x; 1.9571x over previous
//
#include <hip/hip_runtime.h>
#include <hip/hip_bf16.h>
#include <stdint.h>

// ---------------------------------------------------------------------------
// MixModel fused kernel (MI355X / gfx950), round 7.
//
// Round-5 structure (proven correct) + AGPR pinning WITHOUT inline-asm MFMA
// (round 6's asm MFMA bypassed the compiler's MAI hazard handling -> NaN).
// Tile-1 message chunks are *defined* via trivial `v_accvgpr_write_b32` asm
// ("=a" constraint) so their live ranges get AGPR class; all MFMAs remain
// builtins (hazards compiler-managed) and consume the AGPR bank through the
// AV operand class (or cheap scoreboarded copies).
//  VGPR side: msg tile0 (162) + snapshots/transients ~= 240
//  AGPR side: msg tile1 (162)
// ---------------------------------------------------------------------------

typedef __attribute__((ext_vector_type(4))) float    f32x4;
typedef __attribute__((ext_vector_type(4))) _Float16 f16x4;
typedef __attribute__((ext_vector_type(8))) _Float16 f16x8;
typedef __attribute__((ext_vector_type(2))) unsigned int u32x2;
typedef unsigned long long u64;
typedef unsigned int u32;

#define STEP_BYTES 55296           // 9 jt * 6 slices * 64 lanes * 16B
#define CMN_BYTES  45056           // padded; real 41472
#define WS_LAYER   (54*STEP_BYTES) // 2,985,984
#define LDS_TOTAL  (2*STEP_BYTES)  // 110,592

__device__ __forceinline__ unsigned short f2h(float f) {
  return __builtin_bit_cast(unsigned short, (_Float16)f);
}
__device__ __forceinline__ u64 as_u64(f16x4 v) { return __builtin_bit_cast(u64, v); }
__device__ __forceinline__ f16x4 as_f16x4(u64 v) { return __builtin_bit_cast(f16x4, v); }
__device__ __forceinline__ f16x4 pair_f16x4(u32 lo, u32 hi) {
  u32x2 w; w[0] = lo; w[1] = hi;
  return __builtin_bit_cast(f16x4, w);
}

__device__ __forceinline__ f32x4 mfma16(f16x4 a, f16x4 b, f32x4 c) {
#if __has_builtin(__builtin_amdgcn_mfma_f32_16x16x16f16)
  return __builtin_amdgcn_mfma_f32_16x16x16f16(a, b, c, 0, 0, 0);
#else
  asm("v_mfma_f32_16x16x16_f16 %0, %1, %2, %0" : "+v"(c) : "v"(a), "v"(b));
  return c;
#endif
}

// pin a 32-bit value into an AGPR (definition point); consumers are builtin
// MFMAs whose A/B operands accept AGPRs (AV class) on gfx90a+.
__device__ __forceinline__ u32 to_agpr(u32 v) {
  u32 r;
  asm("v_accvgpr_write_b32 %0, %1" : "=a"(r) : "v"(v));
  return r;
}
__device__ __forceinline__ u32 agpr_zero() {
  u32 r;
  asm("v_accvgpr_write_b32 %0, 0" : "=a"(r));
  return r;
}

// static feature value for (sample b, position o, padded k-index kidx in [0,48))
// [0..8] mask row o | [9..17] board ch0 row o | [18..26] board ch1 row o
// [27..35] g0 (ch0 row 9) | [36..44] g1 (ch1 row 9) | [45..47] zero pad
__device__ __forceinline__ float static_feat(const float* __restrict__ mask,
                                             const float* __restrict__ board,
                                             int b, int o, int kidx) {
  if (kidx < 9)  return mask [b*81  + o*9 + kidx];
  if (kidx < 18) return board[b*180 +       o*9 + (kidx - 9)];
  if (kidx < 27) return board[b*180 + 90 +  o*9 + (kidx - 18)];
  if (kidx < 36) return board[b*180 +       81 + (kidx - 27)];
  if (kidx < 45) return board[b*180 + 90 +  81 + (kidx - 36)];
  return 0.f;
}

// async stage one step's fragment block into LDS (wave-uniform dest + lane*16)
__device__ __forceinline__ void stage_step(int s, const unsigned char* __restrict__ ws,
                                           unsigned char* dstlds, int tid) {
  const unsigned char* src = (s < 54) ? (ws + (size_t)s * STEP_BYTES)
                                      : (ws + WS_LAYER + (size_t)(s - 54) * CMN_BYTES);
  const int n16 = (s < 54) ? (STEP_BYTES / 16) : (CMN_BYTES / 16);
  const int ubase = tid & ~63;
  for (int k = 0; k * 256 < n16; ++k) {
    const int idx = k * 256 + tid;
    if (idx < n16) {  // wave-uniform branch (n16 % 64 == 0)
      __builtin_amdgcn_global_load_lds(
          (const __attribute__((address_space(1))) void*)(src + (size_t)idx * 16),
          (__attribute__((address_space(3))) void*)(dstlds + (size_t)(k * 256 + ubase) * 16),
          16, 0, 0);
    }
  }
}

// one (layer, position) step: 9 jt output tiles, K=192 as 12 K16 chunks.
// chunk order: 0=st0(bits), 1=st1(bits), 2=stc(+bias lane), 3..11 = messages.
// msg0 = tile-0 bank (VGPR, u64/chunk), msg1 = tile-1 bank (AGPR, 2xu32/chunk).
template<int P, int O>
__device__ __forceinline__ void do_position(const unsigned char* __restrict__ wb,
    u64 (&msg0)[9][9], u32 (&msg1)[9][9][2], const u64 (&sb)[2], const u32 (&sb8)[2],
    const f16x4 (&stc)[2], int lane)
{
  // rebuild position-O static fragments from the bitmask bank (values 0/1)
  f16x4 st0[2], st1[2];
#pragma unroll
  for (int t = 0; t < 2; ++t) {
    const u32 byt = (O < 8) ? ((u32)(sb[t] >> (O * 8)) & 0xFFu) : sb8[t];
#pragma unroll
    for (int e = 0; e < 4; ++e) {
      st0[t][e] = (_Float16)(float)((byt >> e) & 1u);
      st1[t][e] = (_Float16)(float)((byt >> (4 + e)) & 1u);
    }
  }

  // snapshot the message chunks (read set == write set within this step)
  u64 msgc0[9];
  u32 msgc1[9][2];
#pragma unroll
  for (int i = 0; i < 9; ++i) {
    msgc0[i]    = P ? msg0[O][i]    : msg0[i][O];
    msgc1[i][0] = P ? msg1[O][i][0] : msg1[i][O][0];
    msgc1[i][1] = P ? msg1[O][i][1] : msg1[i][O][1];
  }

  const unsigned char* abase = wb + (size_t)lane * 16;
#pragma unroll
  for (int j = 0; j < 9; ++j) {
    f32x4 acc0 = 0.f, acc1 = 0.f;
#pragma unroll
    for (int sp = 0; sp < 6; ++sp) {
      const f16x8 af = *(const f16x8*)(abase + j * 6144 + sp * 1024);
      const f16x4 alo = __builtin_shufflevector(af, af, 0, 1, 2, 3);
      const f16x4 ahi = __builtin_shufflevector(af, af, 4, 5, 6, 7);
      const int c0 = 2 * sp, c1 = 2 * sp + 1;
      // even chunk (c0): 0 -> st0, 2 -> stc, else message chunk c0-3
      if (c0 == 0) {
        acc0 = mfma16(alo, st0[0], acc0);
        acc1 = mfma16(alo, st0[1], acc1);
      } else if (c0 == 2) {
        acc0 = mfma16(alo, stc[0], acc0);
        acc1 = mfma16(alo, stc[1], acc1);
      } else {
        acc0 = mfma16(alo, as_f16x4(msgc0[c0 - 3]), acc0);
        acc1 = mfma16(alo, pair_f16x4(msgc1[c0 - 3][0], msgc1[c0 - 3][1]), acc1);
      }
      // odd chunk (c1): 1 -> st1, else message chunk c1-3
      if (c1 == 1) {
        acc0 = mfma16(ahi, st1[0], acc0);
        acc1 = mfma16(ahi, st1[1], acc1);
      } else {
        acc0 = mfma16(ahi, as_f16x4(msgc0[c1 - 3]), acc0);
        acc1 = mfma16(ahi, pair_f16x4(msgc1[c1 - 3][0], msgc1[c1 - 3][1]), acc1);
      }
    }
    f16x4 h0, h1;
#pragma unroll
    for (int r = 0; r < 4; ++r) {
      h0[r] = (_Float16)fmaxf(acc0[r], 0.f);
      h1[r] = (_Float16)fmaxf(acc1[r], 0.f);
    }
    const u32x2 h1w = __builtin_bit_cast(u32x2, h1);
    const u32 n0 = to_agpr(h1w[0]);
    const u32 n1 = to_agpr(h1w[1]);
    if (P) { msg0[O][j] = as_u64(h0); msg1[O][j][0] = n0; msg1[O][j][1] = n1; }
    else   { msg0[j][O] = as_u64(h0); msg1[j][O][0] = n0; msg1[j][O][1] = n1; }
  }
}

__global__ __launch_bounds__(256, 1) void mix_main(
    const float* __restrict__ mask, const float* __restrict__ board,
    const float* __restrict__ common_b, const float* __restrict__ wdl_w,
    const float* __restrict__ wdl_b, const unsigned char* __restrict__ ws,
    float* __restrict__ out, int Bt)
{
  extern __shared__ unsigned char lds[];
  const int tid = threadIdx.x;
  const int lane = tid & 63;
  const int wid = tid >> 6;
  const int s15 = lane & 15, hq = lane >> 4;
  const int b0 = blockIdx.x * 128 + wid * 32;

  stage_step(0, ws, lds, tid);   // prologue stage of step 0 (buffer parity 0)

  u64 msg0[9][9];
  u32 msg1[9][9][2];
#pragma unroll
  for (int a = 0; a < 9; ++a)
#pragma unroll
    for (int b = 0; b < 9; ++b) {
      msg0[a][b] = 0ull;
      msg1[a][b][0] = agpr_zero();
      msg1[a][b][1] = agpr_zero();
    }

  // static bitmask bank: bit (o*8 + c*4 + e) of sb[t] (o<8) / sb8[t] (o=8)
  // holds static_feat(b, o, c*16 + 4*hq + e) — all mask/board values are 0/1.
  u64 sb[2] = {0ull, 0ull};
  u32 sb8[2] = {0u, 0u};
#pragma unroll
  for (int t = 0; t < 2; ++t) {
    const int b = b0 + t * 16 + s15;
#pragma unroll
    for (int o = 0; o < 9; ++o)
#pragma unroll
      for (int e = 0; e < 4; ++e) {
        const u32 bit0 = static_feat(mask, board, b, o,      4 * hq + e) > 0.5f;
        const u32 bit1 = static_feat(mask, board, b, o, 16 + 4 * hq + e) > 0.5f;
        if (o < 8) sb[t] |= ((u64)bit0 << (o * 8 + e)) | ((u64)bit1 << (o * 8 + 4 + e));
        else       sb8[t] |= (bit0 << e) | (bit1 << (4 + e));
      }
  }

  // position-independent chunk 2 (g0 tail + g1); pad lane k=45 carries 1.0
  // so the layer bias (stored in weight row 45) rides the MFMA.
  f16x4 stc[2];
#pragma unroll
  for (int t = 0; t < 2; ++t) {
    const int b = b0 + t * 16 + s15;
#pragma unroll
    for (int e = 0; e < 4; ++e) {
      const int kidx = 32 + 4 * hq + e;
      stc[t][e] = (_Float16)((kidx == 45) ? 1.f : static_feat(mask, board, b, 0, kidx));
    }
  }

#define DO_POS(P, O) { \
    asm volatile("s_waitcnt vmcnt(0)" ::: "memory"); \
    __syncthreads(); \
    const int step = base + (P) * 9 + (O); \
    if (step + 1 < 64) \
      stage_step(step + 1, ws, lds + (size_t)((step + 1) & 1) * STEP_BYTES, tid); \
    do_position<P, O>(lds + (size_t)(step & 1) * STEP_BYTES, msg0, msg1, sb, sb8, stc, lane); \
  }

  for (int dp = 0; dp < 3; ++dp) {
    const int base = dp * 18;
    DO_POS(0,0) DO_POS(0,1) DO_POS(0,2) DO_POS(0,3) DO_POS(0,4)
    DO_POS(0,5) DO_POS(0,6) DO_POS(0,7) DO_POS(0,8)
    DO_POS(1,0) DO_POS(1,1) DO_POS(1,2) DO_POS(1,3) DO_POS(1,4)
    DO_POS(1,5) DO_POS(1,6) DO_POS(1,7) DO_POS(1,8)
  }
#undef DO_POS

  // ---- common layer: (B x 1296) @ (1296 x 145), 10 M-tiles streamed ----
  float pw0[3] = {0.f, 0.f, 0.f}, pw1[3] = {0.f, 0.f, 0.f};
  for (int mt = 0; mt < 10; ++mt) {
    asm volatile("s_waitcnt vmcnt(0)" ::: "memory");
    __syncthreads();
    const int step = 54 + mt;
    if (step + 1 < 64)
      stage_step(step + 1, ws, lds + (size_t)((step + 1) & 1) * STEP_BYTES, tid);
    const unsigned char* cb = lds + (size_t)(step & 1) * STEP_BYTES;
    f32x4 a0 = 0.f, a1 = 0.f;
#pragma unroll
    for (int i = 0; i < 9; ++i) {
#pragma unroll
      for (int p = 0; p < 4; ++p) {
        const f16x8 af = *(const f16x8*)(cb + ((size_t)(i * 4 + p) * 64 + lane) * 16);
        const f16x4 alo = __builtin_shufflevector(af, af, 0, 1, 2, 3);
        const f16x4 ahi = __builtin_shufflevector(af, af, 4, 5, 6, 7);
        a0 = mfma16(alo, as_f16x4(msg0[i][2 * p]),     a0);
        a1 = mfma16(alo, pair_f16x4(msg1[i][2 * p][0], msg1[i][2 * p][1]), a1);
        a0 = mfma16(ahi, as_f16x4(msg0[i][2 * p + 1]), a0);
        a1 = mfma16(ahi, pair_f16x4(msg1[i][2 * p + 1][0], msg1[i][2 * p + 1][1]), a1);
      }
      const f16x4 al = *(const f16x4*)(cb + 36864 + ((size_t)i * 64 + lane) * 8);
      a0 = mfma16(al, as_f16x4(msg0[i][8]), a0);
      a1 = mfma16(al, pair_f16x4(msg1[i][8][0], msg1[i][8][1]), a1);
    }
#pragma unroll
    for (int r = 0; r < 4; ++r) {
      const int c = mt * 16 + 4 * hq + r;
      const float bias = (c < 145) ? common_b[c] : 0.f;
      const float v0 = a0[r] + bias, v1 = a1[r] + bias;
      if (c < 81) {  // policy (no relu)
        out[(size_t)3 * Bt + (size_t)(b0 + s15) * 81 + c]      = v0;
        out[(size_t)3 * Bt + (size_t)(b0 + 16 + s15) * 81 + c] = v1;
      } else if (c < 145) {  // wdl hidden: relu then tiny matmul accumulation
        const float h0 = fmaxf(v0, 0.f), h1 = fmaxf(v1, 0.f);
        const int cc = c - 81;
#pragma unroll
        for (int w = 0; w < 3; ++w) {
          const float wv = wdl_w[cc * 3 + w];
          pw0[w] += h0 * wv;
          pw1[w] += h1 * wv;
        }
      }
    }
  }

  // reduce wdl partials across the 4 lane-quarters (same sample col)
#pragma unroll
  for (int w = 0; w < 3; ++w) {
    float v0 = pw0[w], v1 = pw1[w];
    v0 += __shfl_xor(v0, 16, 64); v0 += __shfl_xor(v0, 32, 64);
    v1 += __shfl_xor(v1, 16, 64); v1 += __shfl_xor(v1, 32, 64);
    if (hq == 0) {
      const float bb = wdl_b[w];
      out[(size_t)(b0 + s15) * 3 + w]      = v0 + bb;
      out[(size_t)(b0 + 16 + s15) * 3 + w] = v1 + bb;
    }
  }
}

// ---- prologue: layer weights -> fp16 A-fragment order -----------------------
// [d*9+o][jt 9][slice 6][lane 64] x 16B ; e<4 -> kc=2s, e>=4 -> kc=2s+1,
// within-chunk k = 4*hq + (e&3). kidx: 0..44 static, 45 = BIAS row, 46..47
// zero, >=48 -> message k = kidx-3.
__global__ __launch_bounds__(256) void conv_layer_w(const float* __restrict__ lw,
                                                    const float* __restrict__ lb,
                                                    unsigned char* __restrict__ dst) {
  const int gid = blockIdx.x * 256 + threadIdx.x;
  if (gid >= 54 * 9 * 6 * 64) return;
  const int lane = gid & 63;
  const int t = gid >> 6;
  const int kp = t % 6, t2 = t / 6;
  const int jp = t2 % 9, dop = t2 / 9;
  const int m = lane & 15, hq = lane >> 4;
  unsigned short v[8];
#pragma unroll
  for (int e = 0; e < 8; ++e) {
    const int kc = kp * 2 + (e >> 2);
    const int kidx = kc * 16 + 4 * hq + (e & 3);
    float f = 0.f;
    if (kidx < 45)        f = lw[((size_t)dop * 189 + kidx) * 144 + jp * 16 + m];
    else if (kidx == 45)  f = lb[(size_t)dop * 144 + jp * 16 + m];
    else if (kidx >= 48)  f = lw[((size_t)dop * 189 + (kidx - 3)) * 144 + jp * 16 + m];
    v[e] = f2h(f);
  }
  const u32 w0 = (u32)v[0] | ((u32)v[1] << 16);
  const u32 w1 = (u32)v[2] | ((u32)v[3] << 16);
  const u32 w2 = (u32)v[4] | ((u32)v[5] << 16);
  const u32 w3 = (u32)v[6] | ((u32)v[7] << 16);
  *(uint4*)(dst + (size_t)gid * 16) = make_uint4(w0, w1, w2, w3);
}

// ---- prologue: common weights -> fp16 A-fragment order ----------------------
// per mt: [(i*4+p)*64+lane]x16B (pairs ci=i*9+2p, i*9+2p+1), then at 36864:
// [i*64+lane]x8B (leftover ci=i*9+8). c_out padded 145->160 with zeros.
__global__ __launch_bounds__(256) void conv_common_w(const float* __restrict__ cw,
                                                     unsigned char* __restrict__ dst) {
  const int gid = blockIdx.x * 256 + threadIdx.x;
  const int NPAIR = 10 * 36 * 64;
  if (gid < NPAIR) {
    const int lane = gid & 63;
    const int t = gid >> 6;
    const int p = t % 4, t2 = t / 4;
    const int i = t2 % 9, mt = t2 / 9;
    const int m = lane & 15, hq = lane >> 4;
    const int c = mt * 16 + m;
    unsigned short v[8];
#pragma unroll
    for (int e = 0; e < 8; ++e) {
      const int ci = i * 9 + 2 * p + (e >> 2);
      const int k = ci * 16 + 4 * hq + (e & 3);
      v[e] = f2h((c < 145) ? cw[(size_t)k * 145 + c] : 0.f);
    }
    const u32 w0 = (u32)v[0] | ((u32)v[1] << 16);
    const u32 w1 = (u32)v[2] | ((u32)v[3] << 16);
    const u32 w2 = (u32)v[4] | ((u32)v[5] << 16);
    const u32 w3 = (u32)v[6] | ((u32)v[7] << 16);
    *(uint4*)(dst + (size_t)WS_LAYER + (size_t)mt * CMN_BYTES
              + ((size_t)(i * 4 + p) * 64 + lane) * 16) = make_uint4(w0, w1, w2, w3);
  } else if (gid < NPAIR + 10 * 9 * 64) {
    const int g = gid - NPAIR;
    const int lane = g & 63;
    const int t = g >> 6;
    const int i = t % 9, mt = t / 9;
    const int m = lane & 15, hq = lane >> 4;
    const int c = mt * 16 + m;
    unsigned short v[4];
#pragma unroll
    for (int e = 0; e < 4; ++e) {
      const int k = (i * 9 + 8) * 16 + 4 * hq + e;
      v[e] = f2h((c < 145) ? cw[(size_t)k * 145 + c] : 0.f);
    }
    const u32 w0 = (u32)v[0] | ((u32)v[1] << 16);
    const u32 w1 = (u32)v[2] | ((u32)v[3] << 16);
    *(uint2*)(dst + (size_t)WS_LAYER + (size_t)mt * CMN_BYTES + 36864
              + ((size_t)i * 64 + lane) * 8) = make_uint2(w0, w1);
  }
}

extern "C" void kernel_launch(void* const* d_in, const int* in_sizes, int n_in,
                              void* d_out, int out_size, void* d_ws, size_t ws_size,
                              hipStream_t stream) {
  const float* mask     = (const float*)d_in[0];
  const float* board    = (const float*)d_in[1];
  const float* layer_w  = (const float*)d_in[2];
  const float* layer_b  = (const float*)d_in[3];
  const float* common_w = (const float*)d_in[4];
  const float* common_b = (const float*)d_in[5];
  const float* wdl_w    = (const float*)d_in[6];
  const float* wdl_b    = (const float*)d_in[7];
  float* out = (float*)d_out;
  unsigned char* ws = (unsigned char*)d_ws;
  const int Bt = in_sizes[0] / 81;   // 65536

  hipLaunchKernelGGL(conv_layer_w, dim3((54 * 9 * 6 * 64) / 256), dim3(256), 0, stream,
                     layer_w, layer_b, ws);
  hipLaunchKernelGGL(conv_common_w, dim3((10 * (36 + 9) * 64 + 255) / 256), dim3(256),
                     0, stream, common_w, ws);
  (void)hipFuncSetAttribute((const void*)mix_main,
                            hipFuncAttributeMaxDynamicSharedMemorySize, LDS_TOTAL);
  hipLaunchKernelGGL(mix_main, dim3(Bt / 128), dim3(256), LDS_TOTAL, stream,
                     mask, board, common_b, wdl_w, wdl_b, ws, out, Bt);
}